// Round 8
// baseline (2517.962 us; speedup 1.0000x reference)
//
#include <hip/hip_runtime.h>
#include <hip/hip_bf16.h>
#include <cstdint>
#include <cstddef>

// Problem constants
#define BB 32
#define TT 256
#define HID 512
// ws layout (float units): see kernel_launch. Key buffers:
//  xq[pos][2048][32] bf16 time-major projections; hT [dir][2][32][512] bf16;
//  flags [dir][32][32] ints.

typedef __attribute__((ext_vector_type(8))) short short8v;   // 8 bf16
typedef __attribute__((ext_vector_type(4))) float float4v;
typedef __attribute__((ext_vector_type(4))) unsigned int uint4v;

__device__ __forceinline__ float bf2f(unsigned short u) {
  return __uint_as_float(((unsigned int)u) << 16);
}
__device__ __forceinline__ unsigned short f2bf(float f) {
  unsigned int x = __float_as_uint(f);
  x += 0x7fffu + ((x >> 16) & 1u);    // RNE
  return (unsigned short)(x >> 16);
}

// coherent (agent-scope, cache-bypass) ops for cross-WG state.
__device__ __forceinline__ void stg4u_cohere(unsigned short* p, uint4v v) {
  asm volatile("global_store_dwordx4 %0, %1, off sc0 sc1"
               :: "v"(p), "v"(v) : "memory");
}
__device__ __forceinline__ void ldg4u_cohere_issue(uint4v& d, const unsigned short* p) {
  asm volatile("global_load_dwordx4 %0, %1, off sc0 sc1"
               : "=v"(d) : "v"(p) : "memory");
}
__device__ __forceinline__ void wait_vm0() {
  asm volatile("s_waitcnt vmcnt(0)" ::: "memory");
  __builtin_amdgcn_sched_barrier(0);
}

// ---------------- embedding + concat -> bf16, K-padded to 384 -------------
__global__ __launch_bounds__(256) void embed_kernel(
    const int* __restrict__ ids, const int* __restrict__ msk,
    const float* __restrict__ emb, const float* __restrict__ memb,
    unsigned short* __restrict__ x0b)
{
  int bt = blockIdx.x;
  int id = ids[bt];
  int m  = msk[bt];
  const float* er = emb  + (size_t)id * 300;
  const float* mr = memb + (size_t)m * 50;
  for (int d = threadIdx.x; d < 384; d += 256) {
    float v = (d < 300) ? er[d] : (d < 350 ? mr[d - 300] : 0.f);
    x0b[(size_t)bt * 384 + d] = f2bf(v);
  }
}

// ---- one-time: dst[n][k] (bf16, Kpad) = W[k][n] for k < Kreal, else 0 ----
__global__ __launch_bounds__(256) void prep_w(
    const float* __restrict__ W, unsigned short* __restrict__ dst,
    int Kreal, int Kpad)
{
  __shared__ float tile[64][65];
  int tid = threadIdx.x;
  int n0 = blockIdx.x * 64;
  int k0 = blockIdx.y * 64;
#pragma unroll
  for (int i = 0; i < 4; ++i) {
    int e = tid + 256 * i;
    int r = e >> 4, c4 = (e & 15) * 4;
    float4 v = make_float4(0.f, 0.f, 0.f, 0.f);
    if (k0 + r < Kreal) v = *(const float4*)(W + (size_t)(k0 + r) * 2048 + n0 + c4);
    tile[r][c4 + 0] = v.x; tile[r][c4 + 1] = v.y;
    tile[r][c4 + 2] = v.z; tile[r][c4 + 3] = v.w;
  }
  __syncthreads();
  int nl = tid >> 2;
  int kg = (tid & 3) * 16;
  unsigned int pk[4], pk2[4];
#pragma unroll
  for (int jj = 0; jj < 4; ++jj) {
    unsigned short lo = f2bf(tile[kg + jj * 2 + 0][nl]);
    unsigned short hi = f2bf(tile[kg + jj * 2 + 1][nl]);
    pk[jj] = (unsigned int)lo | ((unsigned int)hi << 16);
  }
#pragma unroll
  for (int jj = 0; jj < 4; ++jj) {
    unsigned short lo = f2bf(tile[kg + 8 + jj * 2 + 0][nl]);
    unsigned short hi = f2bf(tile[kg + 8 + jj * 2 + 1][nl]);
    pk2[jj] = (unsigned int)lo | ((unsigned int)hi << 16);
  }
  size_t off = (size_t)(n0 + nl) * Kpad + k0 + kg;
  *(uint4*)(dst + off) = make_uint4(pk[0], pk[1], pk[2], pk[3]);
  *(uint4*)(dst + off + 8) = make_uint4(pk2[0], pk2[1], pk2[2], pk2[3]);
}

// ---- MFMA bf16 GEMM -> xq[pos][2048][32] bf16 (R4-validated) -------------
__global__ __launch_bounds__(256) void gemm_xproj(
    const unsigned short* __restrict__ A,    // [8192][Kpad] bf16
    const unsigned short* __restrict__ wxt,  // [2048][Kpad] bf16
    const float* __restrict__ bias,          // [2048]
    unsigned short* __restrict__ xq,         // [256][2048][32] bf16
    int Kpad, int nkb)
{
  __shared__ unsigned short ws_s[128 * 64];
  __shared__ unsigned short xs_s[32 * 64];
  __shared__ float bias_s[128];
  int tid = threadIdx.x;
  int lane = tid & 63;
  int w = tid >> 6;
  int pos = blockIdx.x;
  int n0 = blockIdx.y * 128;
  if (tid < 128) bias_s[tid] = bias[n0 + tid];

  float4v acc[2][2];
#pragma unroll
  for (int i = 0; i < 2; ++i)
#pragma unroll
    for (int j = 0; j < 2; ++j) acc[i][j] = (float4v)0.f;

  int brow = tid >> 3;
  int seg = tid & 7;
  for (int kb = 0; kb < nkb; ++kb) {
    int k0 = kb * 64;
    __syncthreads();
    {
      const unsigned short* src = A + (size_t)(brow * 256 + pos) * Kpad + k0 + seg * 8;
      uint4 v = *(const uint4*)src;
      int o = (brow * 128 + seg * 16) ^ ((brow & 7) << 4);
      *(uint4*)((char*)xs_s + o) = v;
    }
#pragma unroll
    for (int i = 0; i < 4; ++i) {
      int n = i * 32 + brow;
      const unsigned short* src = wxt + (size_t)(n0 + n) * Kpad + k0 + seg * 8;
      uint4 v = *(const uint4*)src;
      int o = (n * 128 + seg * 16) ^ ((n & 7) << 4);
      *(uint4*)((char*)ws_s + o) = v;
    }
    __syncthreads();
#pragma unroll
    for (int kin = 0; kin < 64; kin += 32) {
      int kl = kin + ((lane >> 4) << 3);
      short8v afrag[2], bfrag[2];
#pragma unroll
      for (int nt = 0; nt < 2; ++nt) {
        int nl = w * 32 + nt * 16 + (lane & 15);
        int o = (nl * 128 + kl * 2) ^ ((nl & 7) << 4);
        afrag[nt] = *(const short8v*)((const char*)ws_s + o);
      }
#pragma unroll
      for (int bt = 0; bt < 2; ++bt) {
        int bl = bt * 16 + (lane & 15);
        int o = (bl * 128 + kl * 2) ^ ((bl & 7) << 4);
        bfrag[bt] = *(const short8v*)((const char*)xs_s + o);
      }
#pragma unroll
      for (int nt = 0; nt < 2; ++nt)
#pragma unroll
        for (int bt = 0; bt < 2; ++bt)
          acc[nt][bt] = __builtin_amdgcn_mfma_f32_16x16x32_bf16(
              afrag[nt], bfrag[bt], acc[nt][bt], 0, 0, 0);
    }
  }
  unsigned short* outp = xq + (size_t)pos * 65536;
#pragma unroll
  for (int nt = 0; nt < 2; ++nt) {
#pragma unroll
    for (int bt = 0; bt < 2; ++bt) {
#pragma unroll
      for (int reg = 0; reg < 4; ++reg) {
        int nl = w * 32 + nt * 16 + ((lane >> 4) << 2) + reg;
        int b = bt * 16 + (lane & 15);
        float v = acc[nt][bt][reg] + bias_s[nl];
        outp[(size_t)(n0 + nl) * 32 + b] = f2bf(v);
      }
    }
  }
}

// ================= MFMA bidirectional LSTM recurrence =================
// Grid 64 WGs x 256 thr: wg<32 -> fw, else bw. Each WG owns 16 hidden units
// (64 gate-cols r=q*16+d). LDS: W slice 64KB + h broadcast 32KB + zs 8KB,
// all XOR-swizzled. Per wave: one 16-row tile x both 16-col batch tiles,
// 32 MFMA over K=512. h crosses WGs as bf16 hT[b][k] via sc0sc1 ops.
// Persistent (t1-t0>1): c in regs + 32-flag/dir barrier. Fallback: c in cbuf.
__global__ __launch_bounds__(256) void lstm_mfma(
    const unsigned short* __restrict__ xq_fw, const unsigned short* __restrict__ xq_bw,
    const unsigned short* __restrict__ whT_fw, const unsigned short* __restrict__ whT_bw,
    const int* __restrict__ length,
    unsigned short* __restrict__ out,   // (B,T,1024) bf16
    unsigned short* __restrict__ hT,    // [dir][2][32][512] bf16
    float* __restrict__ cbuf,           // [dir][512][32] f32, fallback only
    int* __restrict__ flags,            // [dir][32][32]
    int t0, int t1)
{
  extern __shared__ char smem[];
  // W: bytes [0, 65536)        [64 rows r=q*16+d][512 k] bf16, swz ^((r&7)<<4)
  // H: bytes [65536, 98304)    [32 b][512 k] bf16, same swz
  float* zs = (float*)(smem + 98304);                        // [64][32] f32
  unsigned short* hb_st = (unsigned short*)(smem + 106496);  // [32][16]
  unsigned short* ob_st = (unsigned short*)(smem + 107520);  // [32][16]
  int tid = threadIdx.x;
  int wg = blockIdx.x;
  int dir = wg >> 5;
  int widx = wg & 31;
  int u0 = widx << 4;
  const unsigned short* xq = dir ? xq_bw : xq_fw;
  const unsigned short* whT = dir ? whT_bw : whT_fw;
  unsigned short* hbase = hT + (size_t)dir * 32768;
  int* dirflags = flags + dir * 1024;
  int* myflag = dirflags + widx * 32;

  // ---- stage W_h slice once: LDS row r=q*16+d <- whT[q*512+u0+d][:] ----
  {
    int seg = tid & 7;
    int rbase = tid >> 3;
#pragma unroll
    for (int rr = 0; rr < 2; ++rr) {
      int r = rr * 32 + rbase;
      int q = r >> 4, d = r & 15;
      const unsigned short* src = whT + (size_t)(q * 512 + u0 + d) * 512 + seg * 8;
      int ob = r * 1024 + seg * 16;
      int sw = (r & 7) << 4;
#pragma unroll
      for (int i = 0; i < 8; ++i) {
        uint4 v = *(const uint4*)(src + i * 64);
        *(uint4*)(smem + ((ob + i * 128) ^ sw)) = v;
      }
    }
  }

  // wave/frag constants
  int lane = tid & 63;
  int w = tid >> 6;
  int arow = w * 16 + (lane & 15);
  int chunk16 = (lane >> 4) << 4;
  int asw = (arow & 7) << 4;
  int bcol = lane & 15;
  int bsw = (bcol & 7) << 4;
  // finalize constants: 2 (unit,batch) items per thread
  int fu = tid >> 5;                  // 0..7 (units fu and fu+8)
  int fb = tid & 31;                  // batch
  int L = length[fb];
  float creg[2] = {0.f, 0.f};

  for (int t = t0; t < t1; ++t) {
    int sl = dir ? (TT - 1 - t) : t;
    const unsigned short* hTr_g = hbase + (size_t)(t & 1) * 16384;
    unsigned short* hTw_g = hbase + (size_t)((t & 1) ^ 1) * 16384;

    // x-projection prefetch (plain loads, cached): units u0+fu, u0+fu+8
    float xv[2][4];
    {
      const unsigned short* xr = xq + (size_t)sl * 65536 + (size_t)(u0 + fu) * 32 + fb;
#pragma unroll
      for (int uu = 0; uu < 2; ++uu)
#pragma unroll
        for (int q = 0; q < 4; ++q)
          xv[uu][q] = bf2f(xr[uu * 256 + q * 16384]);
    }

    // ---- h broadcast stage: coherent 8x16B -> swizzled LDS ----
    {
      int row = tid >> 3;
      const unsigned short* src = hTr_g + row * 512 + (tid & 7) * 8;
      uint4v r0, r1, r2, r3, r4, r5, r6, r7;
      ldg4u_cohere_issue(r0, src + 0 * 64);
      ldg4u_cohere_issue(r1, src + 1 * 64);
      ldg4u_cohere_issue(r2, src + 2 * 64);
      ldg4u_cohere_issue(r3, src + 3 * 64);
      ldg4u_cohere_issue(r4, src + 4 * 64);
      ldg4u_cohere_issue(r5, src + 5 * 64);
      ldg4u_cohere_issue(r6, src + 6 * 64);
      ldg4u_cohere_issue(r7, src + 7 * 64);
      wait_vm0();
      int ob = 65536 + row * 1024 + (tid & 7) * 16;
      int sw = (row & 7) << 4;
      *(uint4v*)(smem + ((ob + 0 * 128) ^ sw)) = r0;
      *(uint4v*)(smem + ((ob + 1 * 128) ^ sw)) = r1;
      *(uint4v*)(smem + ((ob + 2 * 128) ^ sw)) = r2;
      *(uint4v*)(smem + ((ob + 3 * 128) ^ sw)) = r3;
      *(uint4v*)(smem + ((ob + 4 * 128) ^ sw)) = r4;
      *(uint4v*)(smem + ((ob + 5 * 128) ^ sw)) = r5;
      *(uint4v*)(smem + ((ob + 6 * 128) ^ sw)) = r6;
      *(uint4v*)(smem + ((ob + 7 * 128) ^ sw)) = r7;
    }
    __syncthreads();

    // ---- MFMA: z[64 gate-cols][32 b] = Wl(64x512) @ hs(512x32) ----
    float4v acc0 = (float4v)0.f, acc1 = (float4v)0.f;
#pragma unroll
    for (int ks = 0; ks < 16; ++ks) {
      int kb = ks * 64 + chunk16;
      short8v af = *(const short8v*)(smem + (size_t)arow * 1024 + (kb ^ asw));
      short8v bf0 = *(const short8v*)(smem + 65536 + (size_t)bcol * 1024 + (kb ^ bsw));
      short8v bf1 = *(const short8v*)(smem + 65536 + (size_t)(bcol + 16) * 1024 + (kb ^ bsw));
      acc0 = __builtin_amdgcn_mfma_f32_16x16x32_bf16(af, bf0, acc0, 0, 0, 0);
      acc1 = __builtin_amdgcn_mfma_f32_16x16x32_bf16(af, bf1, acc1, 0, 0, 0);
    }
#pragma unroll
    for (int r = 0; r < 4; ++r) {
      int row = w * 16 + ((lane >> 4) << 2) + r;
      zs[row * 32 + bcol] = acc0[r];
      zs[row * 32 + bcol + 16] = acc1[r];
    }
    __syncthreads();

    // ---- finalize: 256 threads x 2 (unit,batch) items ----
    bool active = sl < L;
#pragma unroll
    for (int uu = 0; uu < 2; ++uu) {
      int du = fu + uu * 8;           // unit-in-WG 0..15
      int ug = u0 + du;               // global unit
      float z0 = zs[(0 * 16 + du) * 32 + fb] + xv[uu][0];
      float z1 = zs[(1 * 16 + du) * 32 + fb] + xv[uu][1];
      float z2 = zs[(2 * 16 + du) * 32 + fb] + xv[uu][2];
      float z3 = zs[(3 * 16 + du) * 32 + fb] + xv[uu][3];
      int ho = 65536 + fb * 1024 + ((ug * 2) ^ ((fb & 7) << 4));
      float h_old = bf2f(*(const unsigned short*)(smem + ho));
      float c_old = cbuf ? cbuf[dir * 16384 + ug * 32 + fb] : creg[uu];
      float si = 1.f / (1.f + expf(-z0));
      float sj = tanhf(z1);
      float sf = 1.f / (1.f + expf(-(z2 + 1.f)));
      float so = 1.f / (1.f + expf(-z3));
      float cn = sf * c_old + si * sj;
      float hn = so * tanhf(cn);
      if (active) {
        if (cbuf) cbuf[dir * 16384 + ug * 32 + fb] = cn; else creg[uu] = cn;
      }
      hb_st[fb * 16 + du] = f2bf(active ? hn : h_old);
      ob_st[fb * 16 + du] = f2bf(active ? hn : 0.f);
    }
    __syncthreads();

    if (tid < 32) {
      // wave 0: coherent h broadcast store (2x16B per batch)
      uint4v h0 = *(const uint4v*)(hb_st + tid * 16);
      uint4v h1 = *(const uint4v*)(hb_st + tid * 16 + 8);
      stg4u_cohere(hTw_g + tid * 512 + u0, h0);
      stg4u_cohere(hTw_g + tid * 512 + u0 + 8, h1);
    } else if (tid >= 64 && tid < 96) {
      // wave 1: plain out store (off the flag critical path)
      int b = tid - 64;
      uint4v o0 = *(const uint4v*)(ob_st + b * 16);
      uint4v o1 = *(const uint4v*)(ob_st + b * 16 + 8);
      unsigned short* op = out + (size_t)(b * TT + sl) * 1024 + dir * 512 + u0;
      *(uint4v*)op = o0;
      *(uint4v*)(op + 8) = o1;
    }

    if (t1 - t0 > 1) {
      if (tid < 64) {                 // wave 0 only: drain + post + poll
        wait_vm0();
        if (tid == 0) {
          __hip_atomic_store(myflag, t + 1, __ATOMIC_RELAXED,
                             __HIP_MEMORY_SCOPE_AGENT);
        }
        if (tid < 32) {
          int* f = dirflags + tid * 32;
          while (__hip_atomic_load(f, __ATOMIC_RELAXED,
                                   __HIP_MEMORY_SCOPE_AGENT) < t + 1) {
            __builtin_amdgcn_s_sleep(1);
          }
        }
      }
      __syncthreads();
    }
  }
}

// ---------------- CRF + pooling + final softmax ----------------
__global__ __launch_bounds__(256) void crf_final(
    const unsigned short* __restrict__ out1,   // (B,T,1024) bf16
    const float* __restrict__ crf_w, const float* __restrict__ crf_b,
    const float* __restrict__ trans,
    const int* __restrict__ length,
    const float* __restrict__ lw, const float* __restrict__ lb,
    float* __restrict__ dout)
{
  __shared__ float e[TT][2];
  __shared__ float pw[TT];
  __shared__ float sv[1024];
  __shared__ float red[256];
  int b = blockIdx.x, tid = threadIdx.x;
  int lane = tid & 63, w = tid >> 6;
  const unsigned short* ob = out1 + (size_t)b * TT * 1024;
  for (int t = w; t < TT; t += 4) {
    float a0 = 0.f, a1 = 0.f;
    for (int i = 0; i < 16; ++i) {
      int d = lane + i * 64;
      float v = bf2f(ob[(size_t)t * 1024 + d]);
      a0 += v * crf_w[d * 2];
      a1 += v * crf_w[d * 2 + 1];
    }
    for (int off = 32; off; off >>= 1) {
      a0 += __shfl_down(a0, off);
      a1 += __shfl_down(a1, off);
    }
    if (lane == 0) { e[t][0] = a0 + crf_b[0]; e[t][1] = a1 + crf_b[1]; }
  }
  __syncthreads();
  if (tid == 0) {
    int L = length[b];
    float t00 = trans[0], t01 = trans[1], t10 = trans[2], t11 = trans[3];
    float a0 = e[0][0], a1 = e[0][1];
    {
      float m = fmaxf(a0, a1);
      float e0 = expf(a0 - m), e1 = expf(a1 - m);
      pw[0] = (L > 0) ? (e1 / (e0 + e1)) : 0.f;
    }
    for (int t = 1; t < TT; ++t) {
      if (t < L) {
        float x0 = a0 + t00, y0 = a1 + t10;
        float m0 = fmaxf(x0, y0);
        float n0 = m0 + logf(expf(x0 - m0) + expf(y0 - m0)) + e[t][0];
        float x1 = a0 + t01, y1 = a1 + t11;
        float m1 = fmaxf(x1, y1);
        float n1 = m1 + logf(expf(x1 - m1) + expf(y1 - m1)) + e[t][1];
        a0 = n0; a1 = n1;
        float m = fmaxf(a0, a1);
        float e0 = expf(a0 - m), e1 = expf(a1 - m);
        pw[t] = e1 / (e0 + e1);
      } else {
        pw[t] = 0.f;
      }
    }
  }
  __syncthreads();
  for (int i = 0; i < 4; ++i) {
    int d = tid + i * 256;
    float s = 0.f;
    for (int t = 0; t < TT; ++t) s += pw[t] * bf2f(ob[(size_t)t * 1024 + d]);
    sv[d] = s;
  }
  __syncthreads();
  float v[3];
  for (int c = 0; c < 3; ++c) {
    float s = 0.f;
    for (int i = 0; i < 4; ++i) {
      int d = tid + i * 256;
      s += sv[d] * lw[d * 3 + c];
    }
    red[tid] = s;
    __syncthreads();
    for (int off = 128; off; off >>= 1) {
      if (tid < off) red[tid] += red[tid + off];
      __syncthreads();
    }
    if (tid == 0) v[c] = red[0] + lb[c];
    __syncthreads();
  }
  if (tid == 0) {
    float m = fmaxf(v[0], fmaxf(v[1], v[2]));
    float e0 = expf(v[0] - m), e1 = expf(v[1] - m), e2 = expf(v[2] - m);
    float s = e0 + e1 + e2;
    dout[b * 3 + 0] = e0 / s;
    dout[b * 3 + 1] = e1 / s;
    dout[b * 3 + 2] = e2 / s;
  }
}

#define LSTM_LDS 108544

static void run_layer(const unsigned short* xq_fw, const unsigned short* xq_bw,
                      const unsigned short* whT_fw, const unsigned short* whT_bw,
                      const int* len, unsigned short* out, unsigned short* hT,
                      float* cbuf_, int* flags, hipStream_t stream) {
  // zero hT (128KB) + cbuf (128KB) + flags (8KB), contiguous
  (void)hipMemsetAsync(hT, 0, 131072 + 131072 + 8192, stream);
  const unsigned short* a0 = xq_fw; const unsigned short* a1 = xq_bw;
  const unsigned short* a2 = whT_fw; const unsigned short* a3 = whT_bw;
  const int* a4 = len; unsigned short* a5 = out; unsigned short* a6 = hT;
  float* a7 = nullptr; int* a8 = flags; int a9 = 0, a10 = TT;
  void* args[11] = { &a0, &a1, &a2, &a3, &a4, &a5, &a6, &a7, &a8, &a9, &a10 };
  hipError_t err = hipLaunchCooperativeKernel(
      reinterpret_cast<const void*>(lstm_mfma), dim3(64), dim3(256),
      args, LSTM_LDS, stream);
  if (err != hipSuccess) {
    for (int t = 0; t < TT; ++t) {
      lstm_mfma<<<64, 256, LSTM_LDS, stream>>>(
          xq_fw, xq_bw, whT_fw, whT_bw, len, out, hT, cbuf_, flags, t, t + 1);
    }
  }
}

extern "C" void kernel_launch(void* const* d_in, const int* in_sizes, int n_in,
                              void* d_out, int out_size, void* d_ws, size_t ws_size,
                              hipStream_t stream) {
  (void)in_sizes; (void)n_in; (void)out_size; (void)ws_size;
  const int* ids    = (const int*)d_in[0];
  const int* msk    = (const int*)d_in[1];
  const int* len    = (const int*)d_in[2];
  const float* emb  = (const float*)d_in[3];
  const float* memb = (const float*)d_in[4];
  const float* trans= (const float*)d_in[5];
  const float* w_fw0= (const float*)d_in[6];
  const float* b_fw0= (const float*)d_in[7];
  const float* w_bw0= (const float*)d_in[8];
  const float* b_bw0= (const float*)d_in[9];
  const float* w_fw1= (const float*)d_in[10];
  const float* b_fw1= (const float*)d_in[11];
  const float* w_bw1= (const float*)d_in[12];
  const float* b_bw1= (const float*)d_in[13];
  const float* crf_w= (const float*)d_in[14];
  const float* crf_b= (const float*)d_in[15];
  const float* lw   = (const float*)d_in[16];
  const float* lb   = (const float*)d_in[17];
  float* outp = (float*)d_out;

  float* ws = (float*)d_ws;
  unsigned short* x0b   = (unsigned short*)(ws);
  unsigned short* wxt0f = (unsigned short*)(ws + 1572864);
  unsigned short* wxt0b = (unsigned short*)(ws + 1966080);
  unsigned short* wxt1f = (unsigned short*)(ws + 2359296);
  unsigned short* wxt1b = (unsigned short*)(ws + 3407872);
  unsigned short* whT0f = (unsigned short*)(ws + 4456448);
  unsigned short* whT0b = (unsigned short*)(ws + 4980736);
  unsigned short* whT1f = (unsigned short*)(ws + 5505024);
  unsigned short* whT1b = (unsigned short*)(ws + 6029312);
  unsigned short* xqf   = (unsigned short*)(ws + 6553600);
  unsigned short* xqb   = (unsigned short*)(ws + 14942208);
  unsigned short* out0b = (unsigned short*)(ws + 23330816);
  unsigned short* out1b = (unsigned short*)(ws + 27525120);
  unsigned short* hT    = (unsigned short*)(ws + 31719424);
  float* cbuf_ = ws + 31752192;
  int*   flags = (int*)(ws + 31784960);

  (void)hipFuncSetAttribute(reinterpret_cast<const void*>(lstm_mfma),
                            hipFuncAttributeMaxDynamicSharedMemorySize, LSTM_LDS);

  embed_kernel<<<8192, 256, 0, stream>>>(ids, msk, emb, memb, x0b);

  // one-time weight transpose+cvt: x-projection rows [0,din) and h rows [din,din+512)
  prep_w<<<dim3(32, 6), 256, 0, stream>>>(w_fw0, wxt0f, 350, 384);
  prep_w<<<dim3(32, 6), 256, 0, stream>>>(w_bw0, wxt0b, 350, 384);
  prep_w<<<dim3(32, 16), 256, 0, stream>>>(w_fw1, wxt1f, 1024, 1024);
  prep_w<<<dim3(32, 16), 256, 0, stream>>>(w_bw1, wxt1b, 1024, 1024);
  prep_w<<<dim3(32, 8), 256, 0, stream>>>(w_fw0 + (size_t)350 * 2048, whT0f, 512, 512);
  prep_w<<<dim3(32, 8), 256, 0, stream>>>(w_bw0 + (size_t)350 * 2048, whT0b, 512, 512);
  prep_w<<<dim3(32, 8), 256, 0, stream>>>(w_fw1 + (size_t)1024 * 2048, whT1f, 512, 512);
  prep_w<<<dim3(32, 8), 256, 0, stream>>>(w_bw1 + (size_t)1024 * 2048, whT1b, 512, 512);

  gemm_xproj<<<dim3(256, 16), 256, 0, stream>>>(x0b, wxt0f, b_fw0, xqf, 384, 6);
  gemm_xproj<<<dim3(256, 16), 256, 0, stream>>>(x0b, wxt0b, b_bw0, xqb, 384, 6);

  run_layer(xqf, xqb, whT0f, whT0b, len, out0b, hT, cbuf_, flags, stream);

  gemm_xproj<<<dim3(256, 16), 256, 0, stream>>>(out0b, wxt1f, b_fw1, xqf, 1024, 16);
  gemm_xproj<<<dim3(256, 16), 256, 0, stream>>>(out0b, wxt1b, b_bw1, xqb, 1024, 16);

  run_layer(xqf, xqb, whT1f, whT1b, len, out1b, hT, cbuf_, flags, stream);

  crf_final<<<32, 256, 0, stream>>>(out1b, crf_w, crf_b, trans, len, lw, lb, outp);
}

// Round 9
// 2085.682 us; speedup vs baseline: 1.2073x; 1.2073x over previous
//
#include <hip/hip_runtime.h>
#include <hip/hip_bf16.h>
#include <cstdint>
#include <cstddef>

// Problem constants
#define BB 32
#define TT 256
#define HID 512

typedef __attribute__((ext_vector_type(8))) short short8v;   // 8 bf16
typedef __attribute__((ext_vector_type(4))) float float4v;
typedef __attribute__((ext_vector_type(4))) unsigned int uint4v;

__device__ __forceinline__ float bf2f(unsigned short u) {
  return __uint_as_float(((unsigned int)u) << 16);
}
__device__ __forceinline__ unsigned short f2bf(float f) {
  unsigned int x = __float_as_uint(f);
  x += 0x7fffu + ((x >> 16) & 1u);    // RNE
  return (unsigned short)(x >> 16);
}

// coherent (agent-scope, cache-bypass) ops for cross-WG state.
__device__ __forceinline__ void stg1_cohere(float* p, float v) {
  asm volatile("global_store_dword %0, %1, off sc0 sc1"
               :: "v"(p), "v"(v) : "memory");
}
__device__ __forceinline__ void ldg4u_cohere_issue(uint4v& d, const unsigned short* p) {
  asm volatile("global_load_dwordx4 %0, %1, off sc0 sc1"
               : "=v"(d) : "v"(p) : "memory");
}
__device__ __forceinline__ void wait_vm0() {
  asm volatile("s_waitcnt vmcnt(0)" ::: "memory");
  __builtin_amdgcn_sched_barrier(0);
}

// =============== fused prep: 8 weight transposes + embed + zeroing =========
// blocks [0,2432): 64x64 transpose tiles over 8 jobs
// blocks [2432,3456): embedding (8 rows each)
// blocks [3456,3464): zero cbuf(128KB)+flagsA(16KB)+flagsB(16KB)
__global__ __launch_bounds__(256) void prep_all(
    const float* __restrict__ w_fw0, const float* __restrict__ w_bw0,
    const float* __restrict__ w_fw1, const float* __restrict__ w_bw1,
    unsigned short* __restrict__ wxt0f, unsigned short* __restrict__ wxt0b,
    unsigned short* __restrict__ wxt1f, unsigned short* __restrict__ wxt1b,
    unsigned short* __restrict__ whT0f, unsigned short* __restrict__ whT0b,
    unsigned short* __restrict__ whT1f, unsigned short* __restrict__ whT1b,
    const int* __restrict__ ids, const int* __restrict__ msk,
    const float* __restrict__ emb, const float* __restrict__ memb,
    unsigned short* __restrict__ x0b,
    float* __restrict__ zero_base)
{
  __shared__ float tile[64][65];
  int blk = blockIdx.x;
  int tid = threadIdx.x;
  if (blk < 2432) {
    const float* W; unsigned short* dst; int Kreal, Kpad, base;
    if (blk < 192)       { W = w_fw0; dst = wxt0f; Kreal = 350;  Kpad = 384;  base = 0; }
    else if (blk < 384)  { W = w_bw0; dst = wxt0b; Kreal = 350;  Kpad = 384;  base = 192; }
    else if (blk < 896)  { W = w_fw1; dst = wxt1f; Kreal = 1024; Kpad = 1024; base = 384; }
    else if (blk < 1408) { W = w_bw1; dst = wxt1b; Kreal = 1024; Kpad = 1024; base = 896; }
    else if (blk < 1664) { W = w_fw0 + (size_t)350 * 2048;  dst = whT0f; Kreal = 512; Kpad = 512; base = 1408; }
    else if (blk < 1920) { W = w_bw0 + (size_t)350 * 2048;  dst = whT0b; Kreal = 512; Kpad = 512; base = 1664; }
    else if (blk < 2176) { W = w_fw1 + (size_t)1024 * 2048; dst = whT1f; Kreal = 512; Kpad = 512; base = 1920; }
    else                 { W = w_bw1 + (size_t)1024 * 2048; dst = whT1b; Kreal = 512; Kpad = 512; base = 2176; }
    int rel = blk - base;
    int n0 = (rel & 31) * 64;
    int k0 = (rel >> 5) * 64;
#pragma unroll
    for (int i = 0; i < 4; ++i) {
      int e = tid + 256 * i;
      int r = e >> 4, c4 = (e & 15) * 4;
      float4 v = make_float4(0.f, 0.f, 0.f, 0.f);
      if (k0 + r < Kreal) v = *(const float4*)(W + (size_t)(k0 + r) * 2048 + n0 + c4);
      tile[r][c4 + 0] = v.x; tile[r][c4 + 1] = v.y;
      tile[r][c4 + 2] = v.z; tile[r][c4 + 3] = v.w;
    }
    __syncthreads();
    int nl = tid >> 2;
    int kg = (tid & 3) * 16;
    unsigned int pk[4], pk2[4];
#pragma unroll
    for (int jj = 0; jj < 4; ++jj) {
      unsigned short lo = f2bf(tile[kg + jj * 2 + 0][nl]);
      unsigned short hi = f2bf(tile[kg + jj * 2 + 1][nl]);
      pk[jj] = (unsigned int)lo | ((unsigned int)hi << 16);
    }
#pragma unroll
    for (int jj = 0; jj < 4; ++jj) {
      unsigned short lo = f2bf(tile[kg + 8 + jj * 2 + 0][nl]);
      unsigned short hi = f2bf(tile[kg + 8 + jj * 2 + 1][nl]);
      pk2[jj] = (unsigned int)lo | ((unsigned int)hi << 16);
    }
    size_t off = (size_t)(n0 + nl) * Kpad + k0 + kg;
    *(uint4*)(dst + off) = make_uint4(pk[0], pk[1], pk[2], pk[3]);
    *(uint4*)(dst + off + 8) = make_uint4(pk2[0], pk2[1], pk2[2], pk2[3]);
  } else if (blk < 3456) {
    int r = blk - 2432;
    int bt = r * 8 + (tid >> 5);
    int id = ids[bt];
    int m  = msk[bt];
    const float* er = emb  + (size_t)id * 300;
    const float* mr = memb + (size_t)m * 50;
    for (int d = tid & 31; d < 384; d += 32) {
      float v = (d < 300) ? er[d] : (d < 350 ? mr[d - 300] : 0.f);
      x0b[(size_t)bt * 384 + d] = f2bf(v);
    }
  } else {
    int r = blk - 3456;           // 0..7, 20KB each -> 160KB total
    float4* p = (float4*)zero_base + (size_t)r * 1280 + tid;
#pragma unroll
    for (int i = 0; i < 5; ++i) p[i * 256] = make_float4(0.f, 0.f, 0.f, 0.f);
  }
}

// ---- MFMA bf16 GEMM (fw+bw fused via z) -> xq[pos][2048][32] bf16 --------
__global__ __launch_bounds__(256) void gemm_xproj2(
    const unsigned short* __restrict__ A,     // [8192][Kpad] bf16
    const unsigned short* __restrict__ wxtF, const unsigned short* __restrict__ wxtB,
    const float* __restrict__ biasF, const float* __restrict__ biasB,
    unsigned short* __restrict__ xqF, unsigned short* __restrict__ xqB,
    int Kpad, int nkb)
{
  __shared__ unsigned short ws_s[128 * 64];
  __shared__ unsigned short xs_s[32 * 64];
  __shared__ float bias_s[128];
  int z = blockIdx.z;
  const unsigned short* wxt = z ? wxtB : wxtF;
  const float* bias = z ? biasB : biasF;
  unsigned short* xq = z ? xqB : xqF;
  int tid = threadIdx.x;
  int lane = tid & 63;
  int w = tid >> 6;
  int pos = blockIdx.x;
  int n0 = blockIdx.y * 128;
  if (tid < 128) bias_s[tid] = bias[n0 + tid];

  float4v acc[2][2];
#pragma unroll
  for (int i = 0; i < 2; ++i)
#pragma unroll
    for (int j = 0; j < 2; ++j) acc[i][j] = (float4v)0.f;

  int brow = tid >> 3;
  int seg = tid & 7;
  for (int kb = 0; kb < nkb; ++kb) {
    int k0 = kb * 64;
    __syncthreads();
    {
      const unsigned short* src = A + (size_t)(brow * 256 + pos) * Kpad + k0 + seg * 8;
      uint4 v = *(const uint4*)src;
      int o = (brow * 128 + seg * 16) ^ ((brow & 7) << 4);
      *(uint4*)((char*)xs_s + o) = v;
    }
#pragma unroll
    for (int i = 0; i < 4; ++i) {
      int n = i * 32 + brow;
      const unsigned short* src = wxt + (size_t)(n0 + n) * Kpad + k0 + seg * 8;
      uint4 v = *(const uint4*)src;
      int o = (n * 128 + seg * 16) ^ ((n & 7) << 4);
      *(uint4*)((char*)ws_s + o) = v;
    }
    __syncthreads();
#pragma unroll
    for (int kin = 0; kin < 64; kin += 32) {
      int kl = kin + ((lane >> 4) << 3);
      short8v afrag[2], bfrag[2];
#pragma unroll
      for (int nt = 0; nt < 2; ++nt) {
        int nl = w * 32 + nt * 16 + (lane & 15);
        int o = (nl * 128 + kl * 2) ^ ((nl & 7) << 4);
        afrag[nt] = *(const short8v*)((const char*)ws_s + o);
      }
#pragma unroll
      for (int bt = 0; bt < 2; ++bt) {
        int bl = bt * 16 + (lane & 15);
        int o = (bl * 128 + kl * 2) ^ ((bl & 7) << 4);
        bfrag[bt] = *(const short8v*)((const char*)xs_s + o);
      }
#pragma unroll
      for (int nt = 0; nt < 2; ++nt)
#pragma unroll
        for (int bt = 0; bt < 2; ++bt)
          acc[nt][bt] = __builtin_amdgcn_mfma_f32_16x16x32_bf16(
              afrag[nt], bfrag[bt], acc[nt][bt], 0, 0, 0);
    }
  }
  unsigned short* outp = xq + (size_t)pos * 65536;
#pragma unroll
  for (int nt = 0; nt < 2; ++nt) {
#pragma unroll
    for (int bt = 0; bt < 2; ++bt) {
#pragma unroll
      for (int reg = 0; reg < 4; ++reg) {
        int nl = w * 32 + nt * 16 + ((lane >> 4) << 2) + reg;
        int b = bt * 16 + (lane & 15);
        float v = acc[nt][bt][reg] + bias_s[nl];
        outp[(size_t)(n0 + nl) * 32 + b] = f2bf(v);
      }
    }
  }
}

// ================= MFMA bidirectional LSTM recurrence (R6-proven) ==========
// Grid 128 WGs x 256 thr: wg<64 -> fw, else bw. Each WG owns 8 hidden units
// (32 gate-cols c=q*8+d). W_h slice (32KB bf16) + h broadcast (32KB bf16)
// in LDS, both XOR-swizzled. Per-wave one 16x16 MFMA tile, K=512 (16 MFMA).
// h state crosses WGs as bf16 hT[b][k] via sc0sc1 coherent 16B ops.
// t==0 uses zeros in LDS (no hT pre-zeroing needed).
__global__ __launch_bounds__(256) void lstm_mfma(
    const unsigned short* __restrict__ xq_fw, const unsigned short* __restrict__ xq_bw,
    const unsigned short* __restrict__ whT_fw, const unsigned short* __restrict__ whT_bw,
    const int* __restrict__ length,
    unsigned short* __restrict__ out,   // (B,T,1024) bf16
    unsigned short* __restrict__ hT,    // [dir][2][32][512] bf16
    float* __restrict__ cbuf,           // [dir][512][32] f32, fallback only
    int* __restrict__ flags,            // [dir][64][32] (layer-private area)
    int t0, int t1)
{
  extern __shared__ char smem[];
  // Wl: bytes [0, 32768)       [32 rows c=q*8+d][512 k] bf16, swz ^((row&7)<<4)
  // hs: bytes [32768, 65536)   [32 b][512 k] bf16, same swz
  float* zs = (float*)(smem + 65536);                       // [32][32] f32
  unsigned short* hb_st = (unsigned short*)(smem + 69632);  // [32][8]
  unsigned short* ob_st = (unsigned short*)(smem + 70144);  // [32][8]
  int tid = threadIdx.x;
  int wg = blockIdx.x;
  int dir = wg >> 6;
  int widx = wg & 63;
  int u0 = widx << 3;
  const unsigned short* xq = dir ? xq_bw : xq_fw;
  const unsigned short* whT = dir ? whT_bw : whT_fw;
  unsigned short* hbase = hT + (size_t)dir * 32768;
  int* dirflags = flags + dir * 2048;
  int* myflag = dirflags + widx * 32;

  // ---- stage W_h slice once: LDS row r=q*8+d <- whT[q*512+u0+d][:] ----
  {
    int r = tid >> 3;
    int q = r >> 3, d = r & 7;
    const unsigned short* src = whT + (size_t)(q * 512 + u0 + d) * 512 + (tid & 7) * 8;
    int ob = r * 1024 + (tid & 7) * 16;
    int sw = (r & 7) << 4;
#pragma unroll
    for (int i = 0; i < 8; ++i) {
      uint4 v = *(const uint4*)(src + i * 64);
      *(uint4*)(smem + ((ob + i * 128) ^ sw)) = v;
    }
  }

  // wave/frag constants
  int lane = tid & 63;
  int w = tid >> 6;
  int wr = w >> 1, wc = w & 1;
  int arow = wr * 16 + (lane & 15);
  int bcol = wc * 16 + (lane & 15);
  int chunk16 = (lane >> 4) << 4;
  int asw = (arow & 7) << 4;
  int bsw = (bcol & 7) << 4;
  // finalize constants
  int fu = tid >> 5;
  int fb = tid & 31;
  int ug = u0 + fu;
  int L = length[fb];
  float creg = 0.f;

  for (int t = t0; t < t1; ++t) {
    int sl = dir ? (TT - 1 - t) : t;
    const unsigned short* hTr_g = hbase + (size_t)(t & 1) * 16384;
    unsigned short* hTw_g = hbase + (size_t)((t & 1) ^ 1) * 16384;

    // x-projection prefetch (plain loads, L2/IC-cached)
    const unsigned short* xr = xq + (size_t)sl * 65536 + (size_t)ug * 32 + fb;
    float xv0 = bf2f(xr[0]);
    float xv1 = bf2f(xr[16384]);
    float xv2 = bf2f(xr[32768]);
    float xv3 = bf2f(xr[49152]);

    // ---- h stage: t==0 -> zeros; else coherent 8x16B -> swizzled LDS ----
    {
      int row = tid >> 3;
      int ob = 32768 + row * 1024 + (tid & 7) * 16;
      int sw = (row & 7) << 4;
      if (t == 0) {
        uint4v zv = (uint4v)0u;
#pragma unroll
        for (int i = 0; i < 8; ++i)
          *(uint4v*)(smem + ((ob + i * 128) ^ sw)) = zv;
      } else {
        const unsigned short* src = hTr_g + row * 512 + (tid & 7) * 8;
        uint4v r0, r1, r2, r3, r4, r5, r6, r7;
        ldg4u_cohere_issue(r0, src + 0 * 64);
        ldg4u_cohere_issue(r1, src + 1 * 64);
        ldg4u_cohere_issue(r2, src + 2 * 64);
        ldg4u_cohere_issue(r3, src + 3 * 64);
        ldg4u_cohere_issue(r4, src + 4 * 64);
        ldg4u_cohere_issue(r5, src + 5 * 64);
        ldg4u_cohere_issue(r6, src + 6 * 64);
        ldg4u_cohere_issue(r7, src + 7 * 64);
        wait_vm0();
        *(uint4v*)(smem + ((ob + 0 * 128) ^ sw)) = r0;
        *(uint4v*)(smem + ((ob + 1 * 128) ^ sw)) = r1;
        *(uint4v*)(smem + ((ob + 2 * 128) ^ sw)) = r2;
        *(uint4v*)(smem + ((ob + 3 * 128) ^ sw)) = r3;
        *(uint4v*)(smem + ((ob + 4 * 128) ^ sw)) = r4;
        *(uint4v*)(smem + ((ob + 5 * 128) ^ sw)) = r5;
        *(uint4v*)(smem + ((ob + 6 * 128) ^ sw)) = r6;
        *(uint4v*)(smem + ((ob + 7 * 128) ^ sw)) = r7;
      }
    }
    __syncthreads();

    // ---- MFMA: z[32 gate-cols][32 b] = Wl(32x512) @ hs(512x32) ----
    float4v acc = (float4v)0.f;
#pragma unroll
    for (int ks = 0; ks < 16; ++ks) {
      int kb = ks * 64 + chunk16;
      short8v af = *(const short8v*)(smem + (size_t)arow * 1024 + (kb ^ asw));
      short8v bf = *(const short8v*)(smem + 32768 + (size_t)bcol * 1024 + (kb ^ bsw));
      acc = __builtin_amdgcn_mfma_f32_16x16x32_bf16(af, bf, acc, 0, 0, 0);
    }
#pragma unroll
    for (int r = 0; r < 4; ++r) {
      int row = wr * 16 + ((lane >> 4) << 2) + r;
      zs[row * 32 + bcol] = acc[r];
    }
    __syncthreads();

    // ---- finalize: all 256 threads, one (unit,batch) each ----
    {
      bool active = sl < L;
      float z0 = zs[(0 * 8 + fu) * 32 + fb] + xv0;
      float z1 = zs[(1 * 8 + fu) * 32 + fb] + xv1;
      float z2 = zs[(2 * 8 + fu) * 32 + fb] + xv2;
      float z3 = zs[(3 * 8 + fu) * 32 + fb] + xv3;
      int ho = 32768 + fb * 1024 + ((ug * 2) ^ ((fb & 7) << 4));
      float h_old = bf2f(*(const unsigned short*)(smem + ho));
      float c_old = cbuf ? ((t > 0) ? cbuf[dir * 16384 + ug * 32 + fb] : 0.f) : creg;
      float si = 1.f / (1.f + expf(-z0));
      float sj = tanhf(z1);
      float sf = 1.f / (1.f + expf(-(z2 + 1.f)));
      float so = 1.f / (1.f + expf(-z3));
      float cn = sf * c_old + si * sj;
      float hn = so * tanhf(cn);
      if (active) {
        if (cbuf) cbuf[dir * 16384 + ug * 32 + fb] = cn; else creg = cn;
      }
      hb_st[fb * 8 + fu] = f2bf(active ? hn : h_old);
      ob_st[fb * 8 + fu] = f2bf(active ? hn : 0.f);
    }
    __syncthreads();

    if (tid < 32) {
      uint4v hv = *(const uint4v*)(hb_st + tid * 8);
      asm volatile("global_store_dwordx4 %0, %1, off sc0 sc1"
                   :: "v"(hTw_g + tid * 512 + u0), "v"(hv) : "memory");
      uint4v ov = *(const uint4v*)(ob_st + tid * 8);
      *(uint4v*)(out + (size_t)(tid * TT + sl) * 1024 + dir * 512 + u0) = ov;
    }

    if (t1 - t0 > 1) {
      wait_vm0();                 // per-wave: h-stores at coherence point
      __syncthreads();
      if (tid == 0) {
        __hip_atomic_store(myflag, t + 1, __ATOMIC_RELAXED,
                           __HIP_MEMORY_SCOPE_AGENT);
      }
      if (tid < 64) {
        int* f = dirflags + tid * 32;
        while (__hip_atomic_load(f, __ATOMIC_RELAXED,
                                 __HIP_MEMORY_SCOPE_AGENT) < t + 1) {
          __builtin_amdgcn_s_sleep(1);
        }
      }
      __syncthreads();
    }
  }
}

// ---------------- CRF + pooling + final softmax ----------------
__global__ __launch_bounds__(256) void crf_final(
    const unsigned short* __restrict__ out1,   // (B,T,1024) bf16
    const float* __restrict__ crf_w, const float* __restrict__ crf_b,
    const float* __restrict__ trans,
    const int* __restrict__ length,
    const float* __restrict__ lw, const float* __restrict__ lb,
    float* __restrict__ dout)
{
  __shared__ float e[TT][2];
  __shared__ float pw[TT];
  __shared__ float sv[1024];
  __shared__ float red[256];
  int b = blockIdx.x, tid = threadIdx.x;
  int lane = tid & 63, w = tid >> 6;
  const unsigned short* ob = out1 + (size_t)b * TT * 1024;
  for (int t = w; t < TT; t += 4) {
    float a0 = 0.f, a1 = 0.f;
    for (int i = 0; i < 16; ++i) {
      int d = lane + i * 64;
      float v = bf2f(ob[(size_t)t * 1024 + d]);
      a0 += v * crf_w[d * 2];
      a1 += v * crf_w[d * 2 + 1];
    }
    for (int off = 32; off; off >>= 1) {
      a0 += __shfl_down(a0, off);
      a1 += __shfl_down(a1, off);
    }
    if (lane == 0) { e[t][0] = a0 + crf_b[0]; e[t][1] = a1 + crf_b[1]; }
  }
  __syncthreads();
  if (tid == 0) {
    int L = length[b];
    float t00 = trans[0], t01 = trans[1], t10 = trans[2], t11 = trans[3];
    float a0 = e[0][0], a1 = e[0][1];
    {
      float m = fmaxf(a0, a1);
      float e0 = expf(a0 - m), e1 = expf(a1 - m);
      pw[0] = (L > 0) ? (e1 / (e0 + e1)) : 0.f;
    }
    for (int t = 1; t < TT; ++t) {
      if (t < L) {
        float x0 = a0 + t00, y0 = a1 + t10;
        float m0 = fmaxf(x0, y0);
        float n0 = m0 + logf(expf(x0 - m0) + expf(y0 - m0)) + e[t][0];
        float x1 = a0 + t01, y1 = a1 + t11;
        float m1 = fmaxf(x1, y1);
        float n1 = m1 + logf(expf(x1 - m1) + expf(y1 - m1)) + e[t][1];
        a0 = n0; a1 = n1;
        float m = fmaxf(a0, a1);
        float e0 = expf(a0 - m), e1 = expf(a1 - m);
        pw[t] = e1 / (e0 + e1);
      } else {
        pw[t] = 0.f;
      }
    }
  }
  __syncthreads();
  for (int i = 0; i < 4; ++i) {
    int d = tid + i * 256;
    float s = 0.f;
    for (int t = 0; t < TT; ++t) s += pw[t] * bf2f(ob[(size_t)t * 1024 + d]);
    sv[d] = s;
  }
  __syncthreads();
  float v[3];
  for (int c = 0; c < 3; ++c) {
    float s = 0.f;
    for (int i = 0; i < 4; ++i) {
      int d = tid + i * 256;
      s += sv[d] * lw[d * 3 + c];
    }
    red[tid] = s;
    __syncthreads();
    for (int off = 128; off; off >>= 1) {
      if (tid < off) red[tid] += red[tid + off];
      __syncthreads();
    }
    if (tid == 0) v[c] = red[0] + lb[c];
    __syncthreads();
  }
  if (tid == 0) {
    float m = fmaxf(v[0], fmaxf(v[1], v[2]));
    float e0 = expf(v[0] - m), e1 = expf(v[1] - m), e2 = expf(v[2] - m);
    float s = e0 + e1 + e2;
    dout[b * 3 + 0] = e0 / s;
    dout[b * 3 + 1] = e1 / s;
    dout[b * 3 + 2] = e2 / s;
  }
}

#define LSTM_LDS 70656

static void run_layer(const unsigned short* xq_fw, const unsigned short* xq_bw,
                      const unsigned short* whT_fw, const unsigned short* whT_bw,
                      const int* len, unsigned short* out, unsigned short* hT,
                      float* cbuf_, int* flags, hipStream_t stream) {
  const unsigned short* a0 = xq_fw; const unsigned short* a1 = xq_bw;
  const unsigned short* a2 = whT_fw; const unsigned short* a3 = whT_bw;
  const int* a4 = len; unsigned short* a5 = out; unsigned short* a6 = hT;
  float* a7 = nullptr; int* a8 = flags; int a9 = 0, a10 = TT;
  void* args[11] = { &a0, &a1, &a2, &a3, &a4, &a5, &a6, &a7, &a8, &a9, &a10 };
  hipError_t err = hipLaunchCooperativeKernel(
      reinterpret_cast<const void*>(lstm_mfma), dim3(128), dim3(256),
      args, LSTM_LDS, stream);
  if (err != hipSuccess) {
    for (int t = 0; t < TT; ++t) {
      lstm_mfma<<<128, 256, LSTM_LDS, stream>>>(
          xq_fw, xq_bw, whT_fw, whT_bw, len, out, hT, cbuf_, flags, t, t + 1);
    }
  }
}

extern "C" void kernel_launch(void* const* d_in, const int* in_sizes, int n_in,
                              void* d_out, int out_size, void* d_ws, size_t ws_size,
                              hipStream_t stream) {
  (void)in_sizes; (void)n_in; (void)out_size; (void)ws_size;
  const int* ids    = (const int*)d_in[0];
  const int* msk    = (const int*)d_in[1];
  const int* len    = (const int*)d_in[2];
  const float* emb  = (const float*)d_in[3];
  const float* memb = (const float*)d_in[4];
  const float* trans= (const float*)d_in[5];
  const float* w_fw0= (const float*)d_in[6];
  const float* b_fw0= (const float*)d_in[7];
  const float* w_bw0= (const float*)d_in[8];
  const float* b_bw0= (const float*)d_in[9];
  const float* w_fw1= (const float*)d_in[10];
  const float* b_fw1= (const float*)d_in[11];
  const float* w_bw1= (const float*)d_in[12];
  const float* b_bw1= (const float*)d_in[13];
  const float* crf_w= (const float*)d_in[14];
  const float* crf_b= (const float*)d_in[15];
  const float* lw   = (const float*)d_in[16];
  const float* lb   = (const float*)d_in[17];
  float* outp = (float*)d_out;

  float* ws = (float*)d_ws;
  unsigned short* x0b   = (unsigned short*)(ws);
  unsigned short* wxt0f = (unsigned short*)(ws + 1572864);
  unsigned short* wxt0b = (unsigned short*)(ws + 1966080);
  unsigned short* wxt1f = (unsigned short*)(ws + 2359296);
  unsigned short* wxt1b = (unsigned short*)(ws + 3407872);
  unsigned short* whT0f = (unsigned short*)(ws + 4456448);
  unsigned short* whT0b = (unsigned short*)(ws + 4980736);
  unsigned short* whT1f = (unsigned short*)(ws + 5505024);
  unsigned short* whT1b = (unsigned short*)(ws + 6029312);
  unsigned short* xqf   = (unsigned short*)(ws + 6553600);
  unsigned short* xqb   = (unsigned short*)(ws + 14942208);
  unsigned short* out0b = (unsigned short*)(ws + 23330816);
  unsigned short* out1b = (unsigned short*)(ws + 27525120);
  unsigned short* hT    = (unsigned short*)(ws + 31719424);
  float* cbuf_ = ws + 31752192;                 // 32768 f (128KB)
  int*   flagsA = (int*)(ws + 31784960);        // 4096 ints (16KB)
  int*   flagsB = (int*)(ws + 31789056);        // 4096 ints (16KB)

  (void)hipFuncSetAttribute(reinterpret_cast<const void*>(lstm_mfma),
                            hipFuncAttributeMaxDynamicSharedMemorySize, LSTM_LDS);

  // one launch: 8 weight transposes + embedding + zero cbuf/flagsA/flagsB
  prep_all<<<3464, 256, 0, stream>>>(
      w_fw0, w_bw0, w_fw1, w_bw1,
      wxt0f, wxt0b, wxt1f, wxt1b,
      whT0f, whT0b, whT1f, whT1b,
      ids, msk, emb, memb, x0b, cbuf_);

  gemm_xproj2<<<dim3(256, 16, 2), 256, 0, stream>>>(
      x0b, wxt0f, wxt0b, b_fw0, b_bw0, xqf, xqb, 384, 6);

  run_layer(xqf, xqb, whT0f, whT0b, len, out0b, hT, cbuf_, flagsA, stream);

  gemm_xproj2<<<dim3(256, 16, 2), 256, 0, stream>>>(
      out0b, wxt1f, wxt1b, b_fw1, b_bw1, xqf, xqb, 1024, 16);

  run_layer(xqf, xqb, whT1f, whT1b, len, out1b, hT, cbuf_, flagsB, stream);

  crf_final<<<32, 256, 0, stream>>>(out1b, crf_w, crf_b, trans, len, lw, lb, outp);
}

// Round 10
// 2003.958 us; speedup vs baseline: 1.2565x; 1.0408x over previous
//
#include <hip/hip_runtime.h>
#include <hip/hip_bf16.h>
#include <cstdint>
#include <cstddef>

// Problem constants
#define BB 32
#define TT 256
#define HID 512

typedef __attribute__((ext_vector_type(8))) short short8v;   // 8 bf16
typedef __attribute__((ext_vector_type(4))) float float4v;
typedef __attribute__((ext_vector_type(4))) unsigned int uint4v;

__device__ __forceinline__ float bf2f(unsigned short u) {
  return __uint_as_float(((unsigned int)u) << 16);
}
__device__ __forceinline__ unsigned short f2bf(float f) {
  unsigned int x = __float_as_uint(f);
  x += 0x7fffu + ((x >> 16) & 1u);    // RNE
  return (unsigned short)(x >> 16);
}
// fast NaN-safe gates (v_exp_f32 based; err ~1e-6 << bf16 noise)
__device__ __forceinline__ float fsig(float x) {
  return 1.f / (1.f + __expf(-x));
}
__device__ __forceinline__ float ftanh(float x) {
  return 1.f - 2.f / (__expf(2.f * x) + 1.f);
}

// coherent (agent-scope, cache-bypass) ops for cross-WG state.
__device__ __forceinline__ void ldg4u_cohere_issue(uint4v& d, const unsigned short* p) {
  asm volatile("global_load_dwordx4 %0, %1, off sc0 sc1"
               : "=v"(d) : "v"(p) : "memory");
}
__device__ __forceinline__ void wait_vm0() {
  asm volatile("s_waitcnt vmcnt(0)" ::: "memory");
  __builtin_amdgcn_sched_barrier(0);
}

// =============== fused prep: 8 weight transposes + embed + zeroing =========
__global__ __launch_bounds__(256) void prep_all(
    const float* __restrict__ w_fw0, const float* __restrict__ w_bw0,
    const float* __restrict__ w_fw1, const float* __restrict__ w_bw1,
    unsigned short* __restrict__ wxt0f, unsigned short* __restrict__ wxt0b,
    unsigned short* __restrict__ wxt1f, unsigned short* __restrict__ wxt1b,
    unsigned short* __restrict__ whT0f, unsigned short* __restrict__ whT0b,
    unsigned short* __restrict__ whT1f, unsigned short* __restrict__ whT1b,
    const int* __restrict__ ids, const int* __restrict__ msk,
    const float* __restrict__ emb, const float* __restrict__ memb,
    unsigned short* __restrict__ x0b,
    float* __restrict__ zero_base)
{
  __shared__ float tile[64][65];
  int blk = blockIdx.x;
  int tid = threadIdx.x;
  if (blk < 2432) {
    const float* W; unsigned short* dst; int Kreal, Kpad, base;
    if (blk < 192)       { W = w_fw0; dst = wxt0f; Kreal = 350;  Kpad = 384;  base = 0; }
    else if (blk < 384)  { W = w_bw0; dst = wxt0b; Kreal = 350;  Kpad = 384;  base = 192; }
    else if (blk < 896)  { W = w_fw1; dst = wxt1f; Kreal = 1024; Kpad = 1024; base = 384; }
    else if (blk < 1408) { W = w_bw1; dst = wxt1b; Kreal = 1024; Kpad = 1024; base = 896; }
    else if (blk < 1664) { W = w_fw0 + (size_t)350 * 2048;  dst = whT0f; Kreal = 512; Kpad = 512; base = 1408; }
    else if (blk < 1920) { W = w_bw0 + (size_t)350 * 2048;  dst = whT0b; Kreal = 512; Kpad = 512; base = 1664; }
    else if (blk < 2176) { W = w_fw1 + (size_t)1024 * 2048; dst = whT1f; Kreal = 512; Kpad = 512; base = 1920; }
    else                 { W = w_bw1 + (size_t)1024 * 2048; dst = whT1b; Kreal = 512; Kpad = 512; base = 2176; }
    int rel = blk - base;
    int n0 = (rel & 31) * 64;
    int k0 = (rel >> 5) * 64;
#pragma unroll
    for (int i = 0; i < 4; ++i) {
      int e = tid + 256 * i;
      int r = e >> 4, c4 = (e & 15) * 4;
      float4 v = make_float4(0.f, 0.f, 0.f, 0.f);
      if (k0 + r < Kreal) v = *(const float4*)(W + (size_t)(k0 + r) * 2048 + n0 + c4);
      tile[r][c4 + 0] = v.x; tile[r][c4 + 1] = v.y;
      tile[r][c4 + 2] = v.z; tile[r][c4 + 3] = v.w;
    }
    __syncthreads();
    int nl = tid >> 2;
    int kg = (tid & 3) * 16;
    unsigned int pk[4], pk2[4];
#pragma unroll
    for (int jj = 0; jj < 4; ++jj) {
      unsigned short lo = f2bf(tile[kg + jj * 2 + 0][nl]);
      unsigned short hi = f2bf(tile[kg + jj * 2 + 1][nl]);
      pk[jj] = (unsigned int)lo | ((unsigned int)hi << 16);
    }
#pragma unroll
    for (int jj = 0; jj < 4; ++jj) {
      unsigned short lo = f2bf(tile[kg + 8 + jj * 2 + 0][nl]);
      unsigned short hi = f2bf(tile[kg + 8 + jj * 2 + 1][nl]);
      pk2[jj] = (unsigned int)lo | ((unsigned int)hi << 16);
    }
    size_t off = (size_t)(n0 + nl) * Kpad + k0 + kg;
    *(uint4*)(dst + off) = make_uint4(pk[0], pk[1], pk[2], pk[3]);
    *(uint4*)(dst + off + 8) = make_uint4(pk2[0], pk2[1], pk2[2], pk2[3]);
  } else if (blk < 3456) {
    int r = blk - 2432;
    int bt = r * 8 + (tid >> 5);
    int id = ids[bt];
    int m  = msk[bt];
    const float* er = emb  + (size_t)id * 300;
    const float* mr = memb + (size_t)m * 50;
    for (int d = tid & 31; d < 384; d += 32) {
      float v = (d < 300) ? er[d] : (d < 350 ? mr[d - 300] : 0.f);
      x0b[(size_t)bt * 384 + d] = f2bf(v);
    }
  } else {
    int r = blk - 3456;           // 0..7, 20KB each -> 160KB total
    float4* p = (float4*)zero_base + (size_t)r * 1280 + tid;
#pragma unroll
    for (int i = 0; i < 5; ++i) p[i * 256] = make_float4(0.f, 0.f, 0.f, 0.f);
  }
}

// ---- MFMA bf16 GEMM (fw+bw fused via z) -> xq[pos][2048][32] bf16 --------
__global__ __launch_bounds__(256) void gemm_xproj2(
    const unsigned short* __restrict__ A,     // [8192][Kpad] bf16
    const unsigned short* __restrict__ wxtF, const unsigned short* __restrict__ wxtB,
    const float* __restrict__ biasF, const float* __restrict__ biasB,
    unsigned short* __restrict__ xqF, unsigned short* __restrict__ xqB,
    int Kpad, int nkb)
{
  __shared__ unsigned short ws_s[128 * 64];
  __shared__ unsigned short xs_s[32 * 64];
  __shared__ float bias_s[128];
  int z = blockIdx.z;
  const unsigned short* wxt = z ? wxtB : wxtF;
  const float* bias = z ? biasB : biasF;
  unsigned short* xq = z ? xqB : xqF;
  int tid = threadIdx.x;
  int lane = tid & 63;
  int w = tid >> 6;
  int pos = blockIdx.x;
  int n0 = blockIdx.y * 128;
  if (tid < 128) bias_s[tid] = bias[n0 + tid];

  float4v acc[2][2];
#pragma unroll
  for (int i = 0; i < 2; ++i)
#pragma unroll
    for (int j = 0; j < 2; ++j) acc[i][j] = (float4v)0.f;

  int brow = tid >> 3;
  int seg = tid & 7;
  for (int kb = 0; kb < nkb; ++kb) {
    int k0 = kb * 64;
    __syncthreads();
    {
      const unsigned short* src = A + (size_t)(brow * 256 + pos) * Kpad + k0 + seg * 8;
      uint4 v = *(const uint4*)src;
      int o = (brow * 128 + seg * 16) ^ ((brow & 7) << 4);
      *(uint4*)((char*)xs_s + o) = v;
    }
#pragma unroll
    for (int i = 0; i < 4; ++i) {
      int n = i * 32 + brow;
      const unsigned short* src = wxt + (size_t)(n0 + n) * Kpad + k0 + seg * 8;
      uint4 v = *(const uint4*)src;
      int o = (n * 128 + seg * 16) ^ ((n & 7) << 4);
      *(uint4*)((char*)ws_s + o) = v;
    }
    __syncthreads();
#pragma unroll
    for (int kin = 0; kin < 64; kin += 32) {
      int kl = kin + ((lane >> 4) << 3);
      short8v afrag[2], bfrag[2];
#pragma unroll
      for (int nt = 0; nt < 2; ++nt) {
        int nl = w * 32 + nt * 16 + (lane & 15);
        int o = (nl * 128 + kl * 2) ^ ((nl & 7) << 4);
        afrag[nt] = *(const short8v*)((const char*)ws_s + o);
      }
#pragma unroll
      for (int bt = 0; bt < 2; ++bt) {
        int bl = bt * 16 + (lane & 15);
        int o = (bl * 128 + kl * 2) ^ ((bl & 7) << 4);
        bfrag[bt] = *(const short8v*)((const char*)xs_s + o);
      }
#pragma unroll
      for (int nt = 0; nt < 2; ++nt)
#pragma unroll
        for (int bt = 0; bt < 2; ++bt)
          acc[nt][bt] = __builtin_amdgcn_mfma_f32_16x16x32_bf16(
              afrag[nt], bfrag[bt], acc[nt][bt], 0, 0, 0);
    }
  }
  unsigned short* outp = xq + (size_t)pos * 65536;
#pragma unroll
  for (int nt = 0; nt < 2; ++nt) {
#pragma unroll
    for (int bt = 0; bt < 2; ++bt) {
#pragma unroll
      for (int reg = 0; reg < 4; ++reg) {
        int nl = w * 32 + nt * 16 + ((lane >> 4) << 2) + reg;
        int b = bt * 16 + (lane & 15);
        float v = acc[nt][bt][reg] + bias_s[nl];
        outp[(size_t)(n0 + nl) * 32 + b] = f2bf(v);
      }
    }
  }
}

// ================= MFMA bidirectional LSTM recurrence ==========
// R8 structure; R9 deltas: (1) out-store on wave1, never drained;
// wave0-only drain+post+poll (HBM out-ack off the critical path);
// (2) fast __expf gates; (3) next-step xv prefetch issued before barrier.
__global__ __launch_bounds__(256) void lstm_mfma(
    const unsigned short* __restrict__ xq_fw, const unsigned short* __restrict__ xq_bw,
    const unsigned short* __restrict__ whT_fw, const unsigned short* __restrict__ whT_bw,
    const int* __restrict__ length,
    unsigned short* __restrict__ out,   // (B,T,1024) bf16
    unsigned short* __restrict__ hT,    // [dir][2][32][512] bf16
    float* __restrict__ cbuf,           // [dir][512][32] f32, fallback only
    int* __restrict__ flags,            // [dir][64][32] (layer-private area)
    int t0, int t1)
{
  extern __shared__ char smem[];
  // Wl: bytes [0, 32768)       [32 rows c=q*8+d][512 k] bf16, swz ^((row&7)<<4)
  // hs: bytes [32768, 65536)   [32 b][512 k] bf16, same swz
  float* zs = (float*)(smem + 65536);                       // [32][32] f32
  unsigned short* hb_st = (unsigned short*)(smem + 69632);  // [32][8]
  unsigned short* ob_st = (unsigned short*)(smem + 70144);  // [32][8]
  int tid = threadIdx.x;
  int wg = blockIdx.x;
  int dir = wg >> 6;
  int widx = wg & 63;
  int u0 = widx << 3;
  const unsigned short* xq = dir ? xq_bw : xq_fw;
  const unsigned short* whT = dir ? whT_bw : whT_fw;
  unsigned short* hbase = hT + (size_t)dir * 32768;
  int* dirflags = flags + dir * 2048;
  int* myflag = dirflags + widx * 32;

  // ---- stage W_h slice once: LDS row r=q*8+d <- whT[q*512+u0+d][:] ----
  {
    int r = tid >> 3;
    int q = r >> 3, d = r & 7;
    const unsigned short* src = whT + (size_t)(q * 512 + u0 + d) * 512 + (tid & 7) * 8;
    int ob = r * 1024 + (tid & 7) * 16;
    int sw = (r & 7) << 4;
#pragma unroll
    for (int i = 0; i < 8; ++i) {
      uint4 v = *(const uint4*)(src + i * 64);
      *(uint4*)(smem + ((ob + i * 128) ^ sw)) = v;
    }
  }

  // wave/frag constants
  int lane = tid & 63;
  int w = tid >> 6;
  int wr = w >> 1, wc = w & 1;
  int arow = wr * 16 + (lane & 15);
  int bcol = wc * 16 + (lane & 15);
  int chunk16 = (lane >> 4) << 4;
  int asw = (arow & 7) << 4;
  int bsw = (bcol & 7) << 4;
  // finalize constants
  int fu = tid >> 5;
  int fb = tid & 31;
  int ug = u0 + fu;
  int L = length[fb];
  float creg = 0.f;

  // xv preload for t0
  const unsigned short* xbase = xq + (size_t)ug * 32 + fb;
  float xv0, xv1, xv2, xv3;
  {
    int sl0 = dir ? (TT - 1 - t0) : t0;
    const unsigned short* xr = xbase + (size_t)sl0 * 65536;
    xv0 = bf2f(xr[0]);
    xv1 = bf2f(xr[16384]);
    xv2 = bf2f(xr[32768]);
    xv3 = bf2f(xr[49152]);
  }

  for (int t = t0; t < t1; ++t) {
    int sl = dir ? (TT - 1 - t) : t;
    const unsigned short* hTr_g = hbase + (size_t)(t & 1) * 16384;
    unsigned short* hTw_g = hbase + (size_t)((t & 1) ^ 1) * 16384;

    // ---- h stage: t==0 -> zeros; else coherent 8x16B -> swizzled LDS ----
    {
      int row = tid >> 3;
      int ob = 32768 + row * 1024 + (tid & 7) * 16;
      int sw = (row & 7) << 4;
      if (t == 0) {
        uint4v zv = (uint4v)0u;
#pragma unroll
        for (int i = 0; i < 8; ++i)
          *(uint4v*)(smem + ((ob + i * 128) ^ sw)) = zv;
      } else {
        const unsigned short* src = hTr_g + row * 512 + (tid & 7) * 8;
        uint4v r0, r1, r2, r3, r4, r5, r6, r7;
        ldg4u_cohere_issue(r0, src + 0 * 64);
        ldg4u_cohere_issue(r1, src + 1 * 64);
        ldg4u_cohere_issue(r2, src + 2 * 64);
        ldg4u_cohere_issue(r3, src + 3 * 64);
        ldg4u_cohere_issue(r4, src + 4 * 64);
        ldg4u_cohere_issue(r5, src + 5 * 64);
        ldg4u_cohere_issue(r6, src + 6 * 64);
        ldg4u_cohere_issue(r7, src + 7 * 64);
        wait_vm0();
        *(uint4v*)(smem + ((ob + 0 * 128) ^ sw)) = r0;
        *(uint4v*)(smem + ((ob + 1 * 128) ^ sw)) = r1;
        *(uint4v*)(smem + ((ob + 2 * 128) ^ sw)) = r2;
        *(uint4v*)(smem + ((ob + 3 * 128) ^ sw)) = r3;
        *(uint4v*)(smem + ((ob + 4 * 128) ^ sw)) = r4;
        *(uint4v*)(smem + ((ob + 5 * 128) ^ sw)) = r5;
        *(uint4v*)(smem + ((ob + 6 * 128) ^ sw)) = r6;
        *(uint4v*)(smem + ((ob + 7 * 128) ^ sw)) = r7;
      }
    }
    __syncthreads();

    // ---- MFMA: z[32 gate-cols][32 b] = Wl(32x512) @ hs(512x32) ----
    float4v acc = (float4v)0.f;
#pragma unroll
    for (int ks = 0; ks < 16; ++ks) {
      int kb = ks * 64 + chunk16;
      short8v af = *(const short8v*)(smem + (size_t)arow * 1024 + (kb ^ asw));
      short8v bf = *(const short8v*)(smem + 32768 + (size_t)bcol * 1024 + (kb ^ bsw));
      acc = __builtin_amdgcn_mfma_f32_16x16x32_bf16(af, bf, acc, 0, 0, 0);
    }
#pragma unroll
    for (int r = 0; r < 4; ++r) {
      int row = wr * 16 + ((lane >> 4) << 2) + r;
      zs[row * 32 + bcol] = acc[r];
    }
    __syncthreads();

    // ---- finalize: all 256 threads, one (unit,batch) each ----
    {
      bool active = sl < L;
      float z0 = zs[(0 * 8 + fu) * 32 + fb] + xv0;
      float z1 = zs[(1 * 8 + fu) * 32 + fb] + xv1;
      float z2 = zs[(2 * 8 + fu) * 32 + fb] + xv2;
      float z3 = zs[(3 * 8 + fu) * 32 + fb] + xv3;
      int ho = 32768 + fb * 1024 + ((ug * 2) ^ ((fb & 7) << 4));
      float h_old = bf2f(*(const unsigned short*)(smem + ho));
      float c_old = cbuf ? ((t > 0) ? cbuf[dir * 16384 + ug * 32 + fb] : 0.f) : creg;
      float si = fsig(z0);
      float sj = ftanh(z1);
      float sf = fsig(z2 + 1.f);
      float so = fsig(z3);
      float cn = sf * c_old + si * sj;
      float hn = so * ftanh(cn);
      if (active) {
        if (cbuf) cbuf[dir * 16384 + ug * 32 + fb] = cn; else creg = cn;
      }
      hb_st[fb * 8 + fu] = f2bf(active ? hn : h_old);
      ob_st[fb * 8 + fu] = f2bf(active ? hn : 0.f);
    }
    __syncthreads();

    if (tid < 32) {
      // wave 0 (lanes 0-31): coherent h broadcast store only
      uint4v hv = *(const uint4v*)(hb_st + tid * 8);
      asm volatile("global_store_dwordx4 %0, %1, off sc0 sc1"
                   :: "v"(hTw_g + tid * 512 + u0), "v"(hv) : "memory");
    } else if (tid >= 64 && tid < 96) {
      // wave 1: plain out store — never drained (stream order covers it)
      int b = tid - 64;
      uint4v ov = *(const uint4v*)(ob_st + b * 8);
      *(uint4v*)(out + (size_t)(b * TT + sl) * 1024 + dir * 512 + u0) = ov;
    }

    // prefetch next step's xv (plain loads; hidden under barrier poll)
    float nxv0 = 0.f, nxv1 = 0.f, nxv2 = 0.f, nxv3 = 0.f;
    if (t + 1 < t1) {
      int sl2 = dir ? (TT - 2 - t) : (t + 1);
      const unsigned short* xr = xbase + (size_t)sl2 * 65536;
      nxv0 = bf2f(xr[0]);
      nxv1 = bf2f(xr[16384]);
      nxv2 = bf2f(xr[32768]);
      nxv3 = bf2f(xr[49152]);
    }

    if (t1 - t0 > 1) {
      if (tid < 64) {               // wave 0 only: drain h-stores + post + poll
        wait_vm0();
        if (tid == 0) {
          __hip_atomic_store(myflag, t + 1, __ATOMIC_RELAXED,
                             __HIP_MEMORY_SCOPE_AGENT);
        }
        int* f = dirflags + tid * 32;
        while (__hip_atomic_load(f, __ATOMIC_RELAXED,
                                 __HIP_MEMORY_SCOPE_AGENT) < t + 1) {
          __builtin_amdgcn_s_sleep(1);
        }
      }
      __syncthreads();
    }
    xv0 = nxv0; xv1 = nxv1; xv2 = nxv2; xv3 = nxv3;
  }
}

// ---------------- CRF + pooling + final softmax ----------------
__global__ __launch_bounds__(256) void crf_final(
    const unsigned short* __restrict__ out1,   // (B,T,1024) bf16
    const float* __restrict__ crf_w, const float* __restrict__ crf_b,
    const float* __restrict__ trans,
    const int* __restrict__ length,
    const float* __restrict__ lw, const float* __restrict__ lb,
    float* __restrict__ dout)
{
  __shared__ float e[TT][2];
  __shared__ float pw[TT];
  __shared__ float sv[1024];
  __shared__ float red[256];
  int b = blockIdx.x, tid = threadIdx.x;
  int lane = tid & 63, w = tid >> 6;
  const unsigned short* ob = out1 + (size_t)b * TT * 1024;
  for (int t = w; t < TT; t += 4) {
    float a0 = 0.f, a1 = 0.f;
    for (int i = 0; i < 16; ++i) {
      int d = lane + i * 64;
      float v = bf2f(ob[(size_t)t * 1024 + d]);
      a0 += v * crf_w[d * 2];
      a1 += v * crf_w[d * 2 + 1];
    }
    for (int off = 32; off; off >>= 1) {
      a0 += __shfl_down(a0, off);
      a1 += __shfl_down(a1, off);
    }
    if (lane == 0) { e[t][0] = a0 + crf_b[0]; e[t][1] = a1 + crf_b[1]; }
  }
  __syncthreads();
  if (tid == 0) {
    int L = length[b];
    float t00 = trans[0], t01 = trans[1], t10 = trans[2], t11 = trans[3];
    float a0 = e[0][0], a1 = e[0][1];
    {
      float m = fmaxf(a0, a1);
      float e0 = __expf(a0 - m), e1 = __expf(a1 - m);
      pw[0] = (L > 0) ? (e1 / (e0 + e1)) : 0.f;
    }
    for (int t = 1; t < TT; ++t) {
      if (t < L) {
        float x0 = a0 + t00, y0 = a1 + t10;
        float m0 = fmaxf(x0, y0);
        float n0 = m0 + __logf(__expf(x0 - m0) + __expf(y0 - m0)) + e[t][0];
        float x1 = a0 + t01, y1 = a1 + t11;
        float m1 = fmaxf(x1, y1);
        float n1 = m1 + __logf(__expf(x1 - m1) + __expf(y1 - m1)) + e[t][1];
        a0 = n0; a1 = n1;
        float m = fmaxf(a0, a1);
        float e0 = __expf(a0 - m), e1 = __expf(a1 - m);
        pw[t] = e1 / (e0 + e1);
      } else {
        pw[t] = 0.f;
      }
    }
  }
  __syncthreads();
  for (int i = 0; i < 4; ++i) {
    int d = tid + i * 256;
    float s = 0.f;
    for (int t = 0; t < TT; ++t) s += pw[t] * bf2f(ob[(size_t)t * 1024 + d]);
    sv[d] = s;
  }
  __syncthreads();
  float v[3];
  for (int c = 0; c < 3; ++c) {
    float s = 0.f;
    for (int i = 0; i < 4; ++i) {
      int d = tid + i * 256;
      s += sv[d] * lw[d * 3 + c];
    }
    red[tid] = s;
    __syncthreads();
    for (int off = 128; off; off >>= 1) {
      if (tid < off) red[tid] += red[tid + off];
      __syncthreads();
    }
    if (tid == 0) v[c] = red[0] + lb[c];
    __syncthreads();
  }
  if (tid == 0) {
    float m = fmaxf(v[0], fmaxf(v[1], v[2]));
    float e0 = __expf(v[0] - m), e1 = __expf(v[1] - m), e2 = __expf(v[2] - m);
    float s = e0 + e1 + e2;
    dout[b * 3 + 0] = e0 / s;
    dout[b * 3 + 1] = e1 / s;
    dout[b * 3 + 2] = e2 / s;
  }
}

#define LSTM_LDS 70656

static void run_layer(const unsigned short* xq_fw, const unsigned short* xq_bw,
                      const unsigned short* whT_fw, const unsigned short* whT_bw,
                      const int* len, unsigned short* out, unsigned short* hT,
                      float* cbuf_, int* flags, hipStream_t stream) {
  const unsigned short* a0 = xq_fw; const unsigned short* a1 = xq_bw;
  const unsigned short* a2 = whT_fw; const unsigned short* a3 = whT_bw;
  const int* a4 = len; unsigned short* a5 = out; unsigned short* a6 = hT;
  float* a7 = nullptr; int* a8 = flags; int a9 = 0, a10 = TT;
  void* args[11] = { &a0, &a1, &a2, &a3, &a4, &a5, &a6, &a7, &a8, &a9, &a10 };
  hipError_t err = hipLaunchCooperativeKernel(
      reinterpret_cast<const void*>(lstm_mfma), dim3(128), dim3(256),
      args, LSTM_LDS, stream);
  if (err != hipSuccess) {
    for (int t = 0; t < TT; ++t) {
      lstm_mfma<<<128, 256, LSTM_LDS, stream>>>(
          xq_fw, xq_bw, whT_fw, whT_bw, len, out, hT, cbuf_, flags, t, t + 1);
    }
  }
}

extern "C" void kernel_launch(void* const* d_in, const int* in_sizes, int n_in,
                              void* d_out, int out_size, void* d_ws, size_t ws_size,
                              hipStream_t stream) {
  (void)in_sizes; (void)n_in; (void)out_size; (void)ws_size;
  const int* ids    = (const int*)d_in[0];
  const int* msk    = (const int*)d_in[1];
  const int* len    = (const int*)d_in[2];
  const float* emb  = (const float*)d_in[3];
  const float* memb = (const float*)d_in[4];
  const float* trans= (const float*)d_in[5];
  const float* w_fw0= (const float*)d_in[6];
  const float* b_fw0= (const float*)d_in[7];
  const float* w_bw0= (const float*)d_in[8];
  const float* b_bw0= (const float*)d_in[9];
  const float* w_fw1= (const float*)d_in[10];
  const float* b_fw1= (const float*)d_in[11];
  const float* w_bw1= (const float*)d_in[12];
  const float* b_bw1= (const float*)d_in[13];
  const float* crf_w= (const float*)d_in[14];
  const float* crf_b= (const float*)d_in[15];
  const float* lw   = (const float*)d_in[16];
  const float* lb   = (const float*)d_in[17];
  float* outp = (float*)d_out;

  float* ws = (float*)d_ws;
  unsigned short* x0b   = (unsigned short*)(ws);
  unsigned short* wxt0f = (unsigned short*)(ws + 1572864);
  unsigned short* wxt0b = (unsigned short*)(ws + 1966080);
  unsigned short* wxt1f = (unsigned short*)(ws + 2359296);
  unsigned short* wxt1b = (unsigned short*)(ws + 3407872);
  unsigned short* whT0f = (unsigned short*)(ws + 4456448);
  unsigned short* whT0b = (unsigned short*)(ws + 4980736);
  unsigned short* whT1f = (unsigned short*)(ws + 5505024);
  unsigned short* whT1b = (unsigned short*)(ws + 6029312);
  unsigned short* xqf   = (unsigned short*)(ws + 6553600);
  unsigned short* xqb   = (unsigned short*)(ws + 14942208);
  unsigned short* out0b = (unsigned short*)(ws + 23330816);
  unsigned short* out1b = (unsigned short*)(ws + 27525120);
  unsigned short* hT    = (unsigned short*)(ws + 31719424);
  float* cbuf_ = ws + 31752192;                 // 32768 f (128KB)
  int*   flagsA = (int*)(ws + 31784960);        // 4096 ints (16KB)
  int*   flagsB = (int*)(ws + 31789056);        // 4096 ints (16KB)

  (void)hipFuncSetAttribute(reinterpret_cast<const void*>(lstm_mfma),
                            hipFuncAttributeMaxDynamicSharedMemorySize, LSTM_LDS);

  // one launch: 8 weight transposes + embedding + zero cbuf/flagsA/flagsB
  prep_all<<<3464, 256, 0, stream>>>(
      w_fw0, w_bw0, w_fw1, w_bw1,
      wxt0f, wxt0b, wxt1f, wxt1b,
      whT0f, whT0b, whT1f, whT1b,
      ids, msk, emb, memb, x0b, cbuf_);

  gemm_xproj2<<<dim3(256, 16, 2), 256, 0, stream>>>(
      x0b, wxt0f, wxt0b, b_fw0, b_bw0, xqf, xqb, 384, 6);

  run_layer(xqf, xqb, whT0f, whT0b, len, out0b, hT, cbuf_, flagsA, stream);

  gemm_xproj2<<<dim3(256, 16, 2), 256, 0, stream>>>(
      out0b, wxt1f, wxt1b, b_fw1, b_bw1, xqf, xqb, 1024, 16);

  run_layer(xqf, xqb, whT1f, whT1b, len, out1b, hT, cbuf_, flagsB, stream);

  crf_final<<<32, 256, 0, stream>>>(out1b, crf_w, crf_b, trans, len, lw, lb, outp);
}